// Round 3
// baseline (593.526 us; speedup 1.0000x reference)
//
#include <hip/hip_runtime.h>
#include <math.h>

#define CDIM 256
#define LDIM 16384
#define NH 8
#define HD 32
#define FFN 512
#define EPS 1e-5f
#define SCALE 0.17677669529663687f  // 1/sqrt(32)

#define RB 64               // rows per chunk
#define NCHUNK 256          // LDIM/RB
#define CPB 8               // chunks per block (persistent pipeline)
#define NGRP 32             // NCHUNK/CPB

typedef __attribute__((ext_vector_type(8))) short short8;
typedef __attribute__((ext_vector_type(4))) float f32x4;

union U8 { short8 s8; unsigned u[4]; };

// f32 -> bf16 (round-to-nearest-even)
__device__ inline unsigned short f2bf(float x) {
    unsigned int u = __float_as_uint(x);
    unsigned int lsb = (u >> 16) & 1u;
    u += 0x7fffu + lsb;
    return (unsigned short)(u >> 16);
}

// ---------------- kernel 0: convert Wip to bf16 fragment layout ----------------
// w1[((t*16 + c)*64 + l)*8 + j] = bf16(Wip[t*32 + (l>>4)*8 + j][c*16 + (l&15)])

__global__ __launch_bounds__(256) void convert_weights(const float* __restrict__ Wip,
                                                       unsigned short* __restrict__ w1) {
    int idx = blockIdx.x * 256 + threadIdx.x;   // 65536 threads
    int j = idx & 7, l = (idx >> 3) & 63, c = (idx >> 9) & 15, t = idx >> 13;
    int k = t * 32 + (l >> 4) * 8 + j;
    int colc = c * 16 + (l & 15);
    w1[idx] = f2bf(Wip[k * CDIM + colc]);
}

// ---------------- kernel 1: q-prep ----------------
// qs = (ln(query)@Wq + bq)*scale; w~[k][h] = sum_d Wkv[k][h*32+d]*qs[h*32+d] (bf16 frag layout);
// qc[h] = sum_d bkv[h*32+d]*qs[h*32+d]

__global__ __launch_bounds__(256) void qprep_kernel(const float* __restrict__ query,
                                                    const float* __restrict__ Wq,
                                                    const float* __restrict__ bq,
                                                    const float* __restrict__ gq,
                                                    const float* __restrict__ beq,
                                                    const float* __restrict__ Wkv,
                                                    const float* __restrict__ bkv,
                                                    float* __restrict__ qs,
                                                    unsigned short* __restrict__ wts,
                                                    float* __restrict__ qcb) {
    int b = blockIdx.x;
    int tid = threadIdx.x;
    int wave = tid >> 6, lane = tid & 63;
    __shared__ float sh[CDIM];
    __shared__ float qsh[CDIM];
    __shared__ float red[8];

    float x = query[b * CDIM + tid];
    float s = x, sq = x * x;
#pragma unroll
    for (int m = 32; m >= 1; m >>= 1) { s += __shfl_xor(s, m, 64); sq += __shfl_xor(sq, m, 64); }
    if (lane == 0) { red[wave] = s; red[4 + wave] = sq; }
    __syncthreads();
    float ts = red[0] + red[1] + red[2] + red[3];
    float tq = red[4] + red[5] + red[6] + red[7];
    float mean = ts * (1.f / CDIM);
    float var = tq * (1.f / CDIM) - mean * mean;
    float rstd = rsqrtf(var + EPS);
    sh[tid] = (x - mean) * rstd * gq[tid] + beq[tid];
    __syncthreads();

    float acc = bq[tid];
    for (int k = 0; k < CDIM; ++k) acc = fmaf(sh[k], Wq[k * CDIM + tid], acc);
    float qv = acc * SCALE;
    qs[b * CDIM + tid] = qv;
    qsh[tid] = qv;
    __syncthreads();

    float wa[8];
#pragma unroll
    for (int h = 0; h < 8; ++h) wa[h] = 0.f;
    const float* wr = Wkv + (size_t)tid * (2 * CDIM);
#pragma unroll
    for (int h = 0; h < 8; ++h)
#pragma unroll
        for (int d = 0; d < 32; ++d)
            wa[h] = fmaf(wr[h * 32 + d], qsh[h * 32 + d], wa[h]);
    // fragment layout: element (t,l,j): t = k>>5, l = ((k>>3)&3)*16 + h, j = k&7
    unsigned short* wb = wts + (b << 12) + ((tid >> 5) << 9) + (((tid >> 3) & 3) << 7) + (tid & 7);
#pragma unroll
    for (int h = 0; h < 8; ++h) wb[h << 3] = f2bf(wa[h]);
#pragma unroll
    for (int h = 8; h < 16; ++h) wb[h << 3] = 0;

    if (tid < 16) {
        float cb = 0.f;
        if (tid < 8) {
#pragma unroll
            for (int d = 0; d < 32; ++d) cb = fmaf(bkv[tid * 32 + d], qsh[tid * 32 + d], cb);
        }
        qcb[b * 16 + tid] = cb;
    }
}

// ---------------- MFMA helpers (XOR-swizzled A tile in LDS) ----------------
// bufA element (row, col): byte = row*512 + ((col*2) ^ ((row&7)<<4))

__device__ inline void mfma_gemm(const unsigned short* __restrict__ smA,
                                 const unsigned short* __restrict__ wsw, int NC, int ctile0,
                                 int lx, int quad, f32x4 acc[4][4]) {
#pragma unroll
    for (int rt = 0; rt < 4; ++rt)
#pragma unroll
        for (int ci = 0; ci < 4; ++ci) acc[rt][ci] = (f32x4){0.f, 0.f, 0.f, 0.f};

    int l = quad * 16 + lx;
    int xv = (lx & 7) << 4;
    const char* base = (const char*)smA;
#pragma unroll
    for (int t = 0; t < 8; ++t) {
        short8 bfrag[4];
#pragma unroll
        for (int ci = 0; ci < 4; ++ci)
            bfrag[ci] = *(const short8*)(wsw + (((size_t)(t * NC + ctile0 + ci)) * 64 + l) * 8);
        int cb = (t * 64 + quad * 16) ^ xv;
        short8 afrag[4];
#pragma unroll
        for (int rt = 0; rt < 4; ++rt)
            afrag[rt] = *(const short8*)(base + (rt * 16 + lx) * 512 + cb);
#pragma unroll
        for (int rt = 0; rt < 4; ++rt)
#pragma unroll
            for (int ci = 0; ci < 4; ++ci)
                acc[rt][ci] = __builtin_amdgcn_mfma_f32_16x16x32_bf16(afrag[rt], bfrag[ci], acc[rt][ci], 0, 0, 0);
    }
}

__device__ inline void mfma_svec(const unsigned short* __restrict__ smA,
                                 const unsigned short* __restrict__ wt,
                                 int lx, int quad, f32x4 accS[4]) {
#pragma unroll
    for (int rt = 0; rt < 4; ++rt) accS[rt] = (f32x4){0.f, 0.f, 0.f, 0.f};
    int l = quad * 16 + lx;
    int xv = (lx & 7) << 4;
    const char* base = (const char*)smA;
#pragma unroll
    for (int t = 0; t < 8; ++t) {
        short8 bf = *(const short8*)(wt + ((t * 64 + l) << 3));
        int cb = (t * 64 + quad * 16) ^ xv;
        short8 af[4];
#pragma unroll
        for (int rt = 0; rt < 4; ++rt)
            af[rt] = *(const short8*)(base + (rt * 16 + lx) * 512 + cb);
#pragma unroll
        for (int rt = 0; rt < 4; ++rt)
            accS[rt] = __builtin_amdgcn_mfma_f32_16x16x32_bf16(af[rt], bf, accS[rt], 0, 0, 0);
    }
}

// convert one staged float4 and write to swizzled LDS tile
__device__ inline void cw(unsigned short* bufc, int tid, int it, float4 v) {
    int i = tid + (it << 8);
    int r = i >> 6, c4 = i & 63;
    int cb = (c4 << 3) ^ ((r & 7) << 4);
    ushort4 u;
    u.x = f2bf(v.x); u.y = f2bf(v.y); u.z = f2bf(v.z); u.w = f2bf(v.w);
    *(ushort4*)((char*)bufc + r * 512 + cb) = u;
}

// ---------------- kernel 2: persistent 8-chunk pipelined main ----------------
// 512 blocks (2/CU, LDS-capped). Per chunk: GEMM1(relu+LN) -> scores via w~ ->
// softmax -> P^T@M. Next chunk's mem rows are loaded to registers before GEMM1
// (latency hidden under the MFMA phase) and written to the other LDS buffer.

__global__ __launch_bounds__(256) void main_kernel(const float* __restrict__ mem,
                                                   const unsigned short* __restrict__ w1,
                                                   const unsigned short* __restrict__ wts,
                                                   const float* __restrict__ bip,
                                                   const float* __restrict__ gip,
                                                   const float* __restrict__ beip,
                                                   const float* __restrict__ qcb,
                                                   const float* __restrict__ ior,
                                                   float* __restrict__ mpart,
                                                   float* __restrict__ msum) {
    int blk = blockIdx.x;
    int b = blk >> 5;            // 32 groups per batch
    int g = blk & 31;
    int chunk0 = g * CPB;
    int tid = threadIdx.x;
    int w = tid >> 6, lane = tid & 63;
    int quad = lane >> 4, lx = lane & 15;

    __shared__ unsigned short bufA[2][RB * 256];   // 64 KiB, XOR-swizzled bf16 tiles
    __shared__ float iorS[2][NH][66];              // double-buffered
    __shared__ float redS[4][RB];
    __shared__ float redQ[4][RB];
    __shared__ float stats[2][RB];

    int col[4];
#pragma unroll
    for (int ci = 0; ci < 4; ++ci) col[ci] = (4 * w + ci) * 16 + lx;
    float bb[4], gg[4], ee[4];
#pragma unroll
    for (int ci = 0; ci < 4; ++ci) { bb[ci] = bip[col[ci]]; gg[ci] = gip[col[ci]]; ee[ci] = beip[col[ci]]; }
    float qcv = qcb[(b << 4) + lx];                // 0 for lx>=8
    const unsigned short* wtb = wts + ((size_t)b << 12);

    int ih = tid >> 6, ir = tid & 63;              // ior staging map (heads ih, ih+4)

    // ---- prologue: stage chunk0 fully ----
    {
        const float4* src = (const float4*)(mem + ((size_t)b * LDIM + (size_t)chunk0 * RB) * CDIM);
        float4 v[16];
#pragma unroll
        for (int it = 0; it < 16; ++it) v[it] = src[tid + (it << 8)];
        float pi0 = ior[((size_t)(b * NH + ih)) * LDIM + chunk0 * RB + ir];
        float pi1 = ior[((size_t)(b * NH + 4 + ih)) * LDIM + chunk0 * RB + ir];
#pragma unroll
        for (int it = 0; it < 16; ++it) cw(&bufA[0][0], tid, it, v[it]);
        iorS[0][ih][ir] = pi0;
        iorS[0][4 + ih][ir] = pi1;
    }

#pragma unroll 1
    for (int i = 0; i < CPB; ++i) {
        int cur = i & 1, nxt = cur ^ 1;
        int chunk = chunk0 + i;
        bool pf = (i + 1 < CPB);
        __syncthreads();                       // #1: bufA[cur]/iorS[cur] ready; bufA[nxt] free

        // prefetch next chunk into registers; lands under GEMM1's MFMA shadow
        float4 va[16];
        float rn0 = 0.f, rn1 = 0.f;
        if (pf) {
            const float4* srcn = (const float4*)(mem + ((size_t)b * LDIM + (size_t)(chunk + 1) * RB) * CDIM);
#pragma unroll
            for (int it = 0; it < 16; ++it) va[it] = srcn[tid + (it << 8)];
            rn0 = ior[((size_t)(b * NH + ih)) * LDIM + (size_t)(chunk + 1) * RB + ir];
            rn1 = ior[((size_t)(b * NH + 4 + ih)) * LDIM + (size_t)(chunk + 1) * RB + ir];
        }

        // ---- GEMM1: relu(mem @ Wip + bip) ----
        f32x4 acc[4][4];
        mfma_gemm(&bufA[cur][0], w1, 16, 4 * w, lx, quad, acc);

#pragma unroll
        for (int rt = 0; rt < 4; ++rt) {
#pragma unroll
            for (int reg = 0; reg < 4; ++reg) {
#pragma unroll
                for (int ci = 0; ci < 4; ++ci)
                    acc[rt][ci][reg] = fmaxf(acc[rt][ci][reg] + bb[ci], 0.f);
                float s2 = acc[rt][0][reg] + acc[rt][1][reg] + acc[rt][2][reg] + acc[rt][3][reg];
                float q2 = acc[rt][0][reg] * acc[rt][0][reg] + acc[rt][1][reg] * acc[rt][1][reg]
                         + acc[rt][2][reg] * acc[rt][2][reg] + acc[rt][3][reg] * acc[rt][3][reg];
#pragma unroll
                for (int m = 8; m >= 1; m >>= 1) { s2 += __shfl_xor(s2, m, 64); q2 += __shfl_xor(q2, m, 64); }
                if (lx == 0) {
                    int row = rt * 16 + quad * 4 + reg;
                    redS[w][row] = s2;
                    redQ[w][row] = q2;
                }
            }
        }
        __syncthreads();                      // #2: redS/redQ visible; va landed
        if (tid < RB) {
            float s2 = redS[0][tid] + redS[1][tid] + redS[2][tid] + redS[3][tid];
            float q2 = redQ[0][tid] + redQ[1][tid] + redQ[2][tid] + redQ[3][tid];
            float mean = s2 * (1.f / CDIM);
            float var = q2 * (1.f / CDIM) - mean * mean;
            stats[0][tid] = mean;
            stats[1][tid] = rsqrtf(var + EPS);
        }
        if (pf) {                             // stage next chunk into free buffer
#pragma unroll
            for (int it = 0; it < 16; ++it) cw(&bufA[nxt][0], tid, it, va[it]);
            iorS[nxt][ih][ir] = rn0;
            iorS[nxt][4 + ih][ir] = rn1;
        }
        __syncthreads();                      // #3: stats visible

        // ---- LN -> bf16 M into bufA[cur] (swizzled) + packed regs for PV ----
        unsigned ypk0[4][4], ypk1[4][4];
        char* bufc = (char*)&bufA[cur][0];
#pragma unroll
        for (int rt = 0; rt < 4; ++rt) {
            float mn[4], rs[4];
#pragma unroll
            for (int reg = 0; reg < 4; ++reg) {
                int row = rt * 16 + quad * 4 + reg;
                mn[reg] = stats[0][row];
                rs[reg] = stats[1][row];
            }
#pragma unroll
            for (int ci = 0; ci < 4; ++ci) {
                unsigned short u0 = f2bf((acc[rt][ci][0] - mn[0]) * rs[0] * gg[ci] + ee[ci]);
                unsigned short u1 = f2bf((acc[rt][ci][1] - mn[1]) * rs[1] * gg[ci] + ee[ci]);
                unsigned short u2 = f2bf((acc[rt][ci][2] - mn[2]) * rs[2] * gg[ci] + ee[ci]);
                unsigned short u3 = f2bf((acc[rt][ci][3] - mn[3]) * rs[3] * gg[ci] + ee[ci]);
                int cb = col[ci] * 2;
                int rbase = rt * 16 + quad * 4;
                *(unsigned short*)(bufc + (rbase + 0) * 512 + (cb ^ (((quad * 4 + 0) & 7) << 4))) = u0;
                *(unsigned short*)(bufc + (rbase + 1) * 512 + (cb ^ (((quad * 4 + 1) & 7) << 4))) = u1;
                *(unsigned short*)(bufc + (rbase + 2) * 512 + (cb ^ (((quad * 4 + 2) & 7) << 4))) = u2;
                *(unsigned short*)(bufc + (rbase + 3) * 512 + (cb ^ (((quad * 4 + 3) & 7) << 4))) = u3;
                ypk0[rt][ci] = (unsigned)u0 | ((unsigned)u1 << 16);
                ypk1[rt][ci] = (unsigned)u2 | ((unsigned)u3 << 16);
            }
        }
        __syncthreads();                      // #4: M visible

        // ---- scores: S = M @ w~ ; col = head (lane&15) ----
        f32x4 accS[4];
        mfma_svec(&bufA[cur][0], wtb, lx, quad, accS);

        float pr[16];
        float cmax = -1e30f;
#pragma unroll
        for (int rt = 0; rt < 4; ++rt)
#pragma unroll
            for (int reg = 0; reg < 4; ++reg) {
                int row = rt * 16 + quad * 4 + reg;
                float sc = (accS[rt][reg] + qcv) * iorS[cur][lx & 7][row];
                pr[rt * 4 + reg] = sc;
                cmax = fmaxf(cmax, sc);
            }
        cmax = fmaxf(cmax, __shfl_xor(cmax, 16, 64));
        cmax = fmaxf(cmax, __shfl_xor(cmax, 32, 64));
        float csum = 0.f;
#pragma unroll
        for (int j = 0; j < 16; ++j) { pr[j] = __expf(pr[j] - cmax); csum += pr[j]; }
        csum += __shfl_xor(csum, 16, 64);
        csum += __shfl_xor(csum, 32, 64);

        // ---- PV: m~(16x256) = P^T(16x64) @ M(64x256), fragments via shuffles ----
        f32x4 accPV[4];
#pragma unroll
        for (int ci = 0; ci < 4; ++ci) accPV[ci] = (f32x4){0.f, 0.f, 0.f, 0.f};

        int srcA = ((quad & 1) << 5) + lx;
        int srcB = srcA + 16;
        bool hiQ = quad >= 2;
#pragma unroll
        for (int t2 = 0; t2 < 2; ++t2) {
            float pe[8];
#pragma unroll
            for (int jj = 0; jj < 4; ++jj) {
                float v0 = __shfl(pr[t2 * 8 + jj], srcA, 64);
                float v1 = __shfl(pr[t2 * 8 + 4 + jj], srcA, 64);
                pe[jj] = hiQ ? v1 : v0;
                float v2 = __shfl(pr[t2 * 8 + jj], srcB, 64);
                float v3 = __shfl(pr[t2 * 8 + 4 + jj], srcB, 64);
                pe[4 + jj] = hiQ ? v3 : v2;
            }
            U8 pa;
            pa.u[0] = (unsigned)f2bf(pe[0]) | ((unsigned)f2bf(pe[1]) << 16);
            pa.u[1] = (unsigned)f2bf(pe[2]) | ((unsigned)f2bf(pe[3]) << 16);
            pa.u[2] = (unsigned)f2bf(pe[4]) | ((unsigned)f2bf(pe[5]) << 16);
            pa.u[3] = (unsigned)f2bf(pe[6]) | ((unsigned)f2bf(pe[7]) << 16);

#pragma unroll
            for (int ci = 0; ci < 4; ++ci) {
                unsigned a0 = (unsigned)__shfl((int)ypk0[t2 * 2][ci], srcA, 64);
                unsigned b0 = (unsigned)__shfl((int)ypk0[t2 * 2 + 1][ci], srcA, 64);
                unsigned a1 = (unsigned)__shfl((int)ypk1[t2 * 2][ci], srcA, 64);
                unsigned b1 = (unsigned)__shfl((int)ypk1[t2 * 2 + 1][ci], srcA, 64);
                unsigned a2 = (unsigned)__shfl((int)ypk0[t2 * 2][ci], srcB, 64);
                unsigned b2 = (unsigned)__shfl((int)ypk0[t2 * 2 + 1][ci], srcB, 64);
                unsigned a3 = (unsigned)__shfl((int)ypk1[t2 * 2][ci], srcB, 64);
                unsigned b3 = (unsigned)__shfl((int)ypk1[t2 * 2 + 1][ci], srcB, 64);
                U8 ub;
                ub.u[0] = hiQ ? b0 : a0;
                ub.u[1] = hiQ ? b1 : a1;
                ub.u[2] = hiQ ? b2 : a2;
                ub.u[3] = hiQ ? b3 : a3;
                accPV[ci] = __builtin_amdgcn_mfma_f32_16x16x32_bf16(pa.s8, ub.s8, accPV[ci], 0, 0, 0);
            }
        }

        // ---- write partials: mpart rows 1024B-aligned; msum compact ----
        if (quad < 2) {
#pragma unroll
            for (int reg = 0; reg < 4; ++reg) {
                int h = quad * 4 + reg;
                float* dst = mpart + ((((size_t)(b * NH + h)) * NCHUNK + chunk) << 8);
#pragma unroll
                for (int ci = 0; ci < 4; ++ci) dst[col[ci]] = accPV[ci][reg];
            }
        }
        if (quad == 0 && lx < 8) {
            float* dst = msum + ((((size_t)(b * NH + lx)) * NCHUNK + chunk) << 1);
            dst[0] = cmax;
            dst[1] = csum;
        }
    }
}

// ---------------- kernel 3: flash-merge partials + V projection ----------------

__global__ __launch_bounds__(256) void combine_kernel(const float* __restrict__ mpart,
                                                      const float* __restrict__ msum,
                                                      const float* __restrict__ Wkv,
                                                      const float* __restrict__ bkv,
                                                      float* __restrict__ attnout) {
    int bh = blockIdx.x;
    int b = bh >> 3, h = bh & 7;
    int tid = threadIdx.x;
    __shared__ float ms[NCHUNK], wf[NCHUNK], mt[CDIM];
    __shared__ float sredA[4];
    __shared__ float ored[8][33];

    const float* basem = mpart + (((size_t)(b * NH + h)) * NCHUNK << 8);
    const float* bases = msum + (((size_t)(b * NH + h)) * NCHUNK << 1);
    ms[tid] = bases[tid << 1];
    __syncthreads();
    float M = -1e30f;
    for (int s = 0; s < NCHUNK; ++s) M = fmaxf(M, ms[s]);
    float e = __expf(ms[tid] - M);
    wf[tid] = e;
    float Sl = bases[(tid << 1) + 1] * e;
#pragma unroll
    for (int m = 32; m >= 1; m >>= 1) Sl += __shfl_xor(Sl, m, 64);
    if ((tid & 63) == 0) sredA[tid >> 6] = Sl;
    __syncthreads();
    float St = sredA[0] + sredA[1] + sredA[2] + sredA[3];

    float acc = 0.f;
    for (int s = 0; s < NCHUNK; ++s) acc = fmaf(wf[s], basem[((size_t)s << 8) + tid], acc);
    mt[tid] = acc / St;
    __syncthreads();

    int d = tid & 31, g = tid >> 5;
    float a2 = 0.f;
    for (int c = g * 32; c < g * 32 + 32; ++c)
        a2 = fmaf(mt[c], Wkv[(size_t)c * (2 * CDIM) + CDIM + h * 32 + d], a2);
    ored[g][d] = a2;
    __syncthreads();
    if (tid < 32) {
        float o = bkv[CDIM + h * 32 + tid];
#pragma unroll
        for (int gg2 = 0; gg2 < 8; ++gg2) o += ored[gg2][tid];
        attnout[b * CDIM + h * HD + tid] = o;
    }
}

// ---------------- kernel 4: x = attn+query; y = x + FFN(ln(x)) ----------------

__global__ __launch_bounds__(256) void epilogue_kernel(const float* __restrict__ attnout,
                                                       const float* __restrict__ query,
                                                       const float* __restrict__ gf,
                                                       const float* __restrict__ bef,
                                                       const float* __restrict__ W1,
                                                       const float* __restrict__ b1,
                                                       const float* __restrict__ W2,
                                                       const float* __restrict__ b2,
                                                       float* __restrict__ out) {
    int b = blockIdx.x;
    int tid = threadIdx.x;
    int wave = tid >> 6, lane = tid & 63;
    __shared__ float sh[FFN];
    __shared__ float red[8];

    float x = attnout[b * CDIM + tid] + query[b * CDIM + tid];
    float s = x, sq = x * x;
#pragma unroll
    for (int m = 32; m >= 1; m >>= 1) { s += __shfl_xor(s, m, 64); sq += __shfl_xor(sq, m, 64); }
    if (lane == 0) { red[wave] = s; red[4 + wave] = sq; }
    __syncthreads();
    float ts = red[0] + red[1] + red[2] + red[3];
    float tq = red[4] + red[5] + red[6] + red[7];
    float mean = ts * (1.f / CDIM);
    float var = tq * (1.f / CDIM) - mean * mean;
    float rstd = rsqrtf(var + EPS);
    sh[tid] = (x - mean) * rstd * gf[tid] + bef[tid];
    __syncthreads();

    float t[2];
#pragma unroll
    for (int i = 0; i < 2; ++i) {
        int f = tid + 256 * i;
        float a = b1[f];
        for (int k = 0; k < CDIM; ++k) a = fmaf(sh[k], W1[k * FFN + f], a);
        t[i] = 0.5f * a * (1.f + erff(a * 0.7071067811865476f));
    }
    __syncthreads();
    sh[tid] = t[0];
    sh[tid + 256] = t[1];
    __syncthreads();

    float y = b2[tid];
    for (int f = 0; f < FFN; ++f) y = fmaf(sh[f], W2[f * CDIM + tid], y);
    out[b * CDIM + tid] = x + y;
}

// ---------------- launch ----------------

extern "C" void kernel_launch(void* const* d_in, const int* in_sizes, int n_in,
                              void* d_out, int out_size, void* d_ws, size_t ws_size,
                              hipStream_t stream) {
    const float* query = (const float*)d_in[0];
    const float* mem   = (const float*)d_in[1];
    const float* ior   = (const float*)d_in[2];
    const float* Wip   = (const float*)d_in[3];
    const float* bip   = (const float*)d_in[4];
    const float* gip   = (const float*)d_in[5];
    const float* beip  = (const float*)d_in[6];
    const float* Wq    = (const float*)d_in[7];
    const float* bq    = (const float*)d_in[8];
    const float* Wkv   = (const float*)d_in[9];
    const float* bkv   = (const float*)d_in[10];
    const float* gq    = (const float*)d_in[11];
    const float* beq   = (const float*)d_in[12];
    const float* gf    = (const float*)d_in[13];
    const float* bef   = (const float*)d_in[14];
    const float* W1    = (const float*)d_in[15];
    const float* b1    = (const float*)d_in[16];
    const float* W2    = (const float*)d_in[17];
    const float* b2    = (const float*)d_in[18];
    float* out = (float*)d_out;

    char* ws = (char*)d_ws;
    float* qs             = (float*)(ws);                      // 16384 B
    float* attnout        = (float*)(ws + 16384);              // 16384 B
    float* qcb            = (float*)(ws + 32768);              // 1024 B
    unsigned short* w1sw  = (unsigned short*)(ws + 33792);     // 131072 B
    unsigned short* wtsw  = (unsigned short*)(ws + 164864);    // 131072 B
    float* mpart          = (float*)(ws + 295936);             // 16*8*256*256*4 = 33554432 B
    float* msum           = (float*)(ws + 295936 + 33554432);  // 16*8*256*2*4 = 131072 B
    // total: 33981440 B (< 34.1 MB proven in round 1)

    const int B = 16;

    convert_weights<<<256, 256, 0, stream>>>(Wip, w1sw);
    qprep_kernel<<<B, 256, 0, stream>>>(query, Wq, bq, gq, beq, Wkv, bkv, qs, wtsw, qcb);
    main_kernel<<<B * NGRP, 256, 0, stream>>>(mem, w1sw, wtsw, bip, gip, beip, qcb, ior, mpart, msum);
    combine_kernel<<<B * NH, 256, 0, stream>>>(mpart, msum, Wkv, bkv, attnout);
    epilogue_kernel<<<B, 256, 0, stream>>>(attnout, query, gf, bef, W1, b1, W2, b2, out);
}

// Round 4
// 553.683 us; speedup vs baseline: 1.0720x; 1.0720x over previous
//
#include <hip/hip_runtime.h>
#include <math.h>

#define CDIM 256
#define LDIM 16384
#define NH 8
#define HD 32
#define FFN 512
#define EPS 1e-5f
#define SCALE 0.17677669529663687f  // 1/sqrt(32)

#define NCHUNK 256          // 64-row chunks per batch (4 waves x 16 rows)

typedef __attribute__((ext_vector_type(8))) short short8;
typedef __attribute__((ext_vector_type(4))) float f32x4;

union U8 { short8 s8; unsigned u[4]; };

// f32 -> bf16 (round-to-nearest-even)
__device__ inline unsigned short f2bf(float x) {
    unsigned int u = __float_as_uint(x);
    unsigned int lsb = (u >> 16) & 1u;
    u += 0x7fffu + lsb;
    return (unsigned short)(u >> 16);
}

// ---------------- kernel 0: convert Wip to bf16 fragment layout ----------------
// w1[((t*16 + c)*64 + l)*8 + j] = bf16(Wip[t*32 + (l>>4)*8 + j][c*16 + (l&15)])

__global__ __launch_bounds__(256) void convert_weights(const float* __restrict__ Wip,
                                                       unsigned short* __restrict__ w1) {
    int idx = blockIdx.x * 256 + threadIdx.x;   // 65536 threads
    int j = idx & 7, l = (idx >> 3) & 63, c = (idx >> 9) & 15, t = idx >> 13;
    int k = t * 32 + (l >> 4) * 8 + j;
    int colc = c * 16 + (l & 15);
    w1[idx] = f2bf(Wip[k * CDIM + colc]);
}

// ---------------- kernel 1: q-prep ----------------
// qs = (ln(query)@Wq + bq)*scale; w~[k][h] = sum_d Wkv[k][h*32+d]*qs[h*32+d] (bf16 frag layout);
// qc[h] = sum_d bkv[h*32+d]*qs[h*32+d]

__global__ __launch_bounds__(256) void qprep_kernel(const float* __restrict__ query,
                                                    const float* __restrict__ Wq,
                                                    const float* __restrict__ bq,
                                                    const float* __restrict__ gq,
                                                    const float* __restrict__ beq,
                                                    const float* __restrict__ Wkv,
                                                    const float* __restrict__ bkv,
                                                    float* __restrict__ qs,
                                                    unsigned short* __restrict__ wts,
                                                    float* __restrict__ qcb) {
    int b = blockIdx.x;
    int tid = threadIdx.x;
    int wave = tid >> 6, lane = tid & 63;
    __shared__ float sh[CDIM];
    __shared__ float qsh[CDIM];
    __shared__ float red[8];

    float x = query[b * CDIM + tid];
    float s = x, sq = x * x;
#pragma unroll
    for (int m = 32; m >= 1; m >>= 1) { s += __shfl_xor(s, m, 64); sq += __shfl_xor(sq, m, 64); }
    if (lane == 0) { red[wave] = s; red[4 + wave] = sq; }
    __syncthreads();
    float ts = red[0] + red[1] + red[2] + red[3];
    float tq = red[4] + red[5] + red[6] + red[7];
    float mean = ts * (1.f / CDIM);
    float var = tq * (1.f / CDIM) - mean * mean;
    float rstd = rsqrtf(var + EPS);
    sh[tid] = (x - mean) * rstd * gq[tid] + beq[tid];
    __syncthreads();

    float acc = bq[tid];
    for (int k = 0; k < CDIM; ++k) acc = fmaf(sh[k], Wq[k * CDIM + tid], acc);
    float qv = acc * SCALE;
    qs[b * CDIM + tid] = qv;
    qsh[tid] = qv;
    __syncthreads();

    float wa[8];
#pragma unroll
    for (int h = 0; h < 8; ++h) wa[h] = 0.f;
    const float* wr = Wkv + (size_t)tid * (2 * CDIM);
#pragma unroll
    for (int h = 0; h < 8; ++h)
#pragma unroll
        for (int d = 0; d < 32; ++d)
            wa[h] = fmaf(wr[h * 32 + d], qsh[h * 32 + d], wa[h]);
    // fragment layout: element (t,l,j): t = k>>5, l = ((k>>3)&3)*16 + h, j = k&7
    unsigned short* wb = wts + (b << 12) + ((tid >> 5) << 9) + (((tid >> 3) & 3) << 7) + (tid & 7);
#pragma unroll
    for (int h = 0; h < 8; ++h) wb[h << 3] = f2bf(wa[h]);
#pragma unroll
    for (int h = 8; h < 16; ++h) wb[h << 3] = 0;

    if (tid < 16) {
        float cb = 0.f;
        if (tid < 8) {
#pragma unroll
            for (int d = 0; d < 32; ++d) cb = fmaf(bkv[tid * 32 + d], qsh[tid * 32 + d], cb);
        }
        qcb[b * 16 + tid] = cb;
    }
}

// ---------------- kernel 2: barrier-free per-wave main ----------------
// Each wave owns a 16-row sub-chunk end-to-end: stage -> GEMM1(relu+LN in-quad)
// -> scores (M @ w~) -> softmax -> PV (P^T @ M, k=16) -> LDS partial.
// One block = 4 waves = one 64-row chunk; single barrier at end flash-merges
// the 4 waves' partials so mpart stays at the 256-chunk layout.
// LDS tile swizzle: byte = r*512 + ((col*2) ^ ((r&7)<<4)).

__global__ __launch_bounds__(256, 4) void main_kernel(const float* __restrict__ mem,
                                                      const unsigned short* __restrict__ w1,
                                                      const unsigned short* __restrict__ wts,
                                                      const float* __restrict__ bip,
                                                      const float* __restrict__ gip,
                                                      const float* __restrict__ beip,
                                                      const float* __restrict__ qcb,
                                                      const float* __restrict__ ior,
                                                      float* __restrict__ mpart,
                                                      float* __restrict__ msum) {
    int blk = blockIdx.x;
    int b = blk >> 8;
    int chunk = blk & 255;
    int tid = threadIdx.x;
    int w = tid >> 6, lane = tid & 63;
    int quad = lane >> 4, lx = lane & 15;

    __shared__ unsigned short bufA[4][4096];   // 4 x 8 KiB swizzled tiles (reused for m~)
    __shared__ float iorS[4][NH][17];
    __shared__ float msL[4][2][8];

    int row0 = chunk * 64 + w * 16;
    unsigned short* myT = &bufA[w][0];
    char* myC = (char*)myT;
    const unsigned short* wtb = wts + ((size_t)b << 12);
    float qcv = qcb[(b << 4) + lx];            // 0 for lx>=8
    int xv = (lx & 7) << 4;

    // ---- stage ior: 8 heads x 16 rows (per wave) ----
    {
        int hh = lane >> 3, rr = lane & 7;
        iorS[w][hh][rr]     = ior[((size_t)(b * NH + hh)) * LDIM + row0 + rr];
        iorS[w][hh][8 + rr] = ior[((size_t)(b * NH + hh)) * LDIM + row0 + 8 + rr];
    }
    // ---- stage mem: 16 rows x 256 cols -> bf16 swizzled tile (2 batches of 8 rows) ----
    {
        const float4* src = (const float4*)(mem + ((size_t)b * LDIM + row0) * CDIM);
        float4 v[8];
#pragma unroll
        for (int it = 0; it < 8; ++it) v[it] = src[it * 64 + lane];
#pragma unroll
        for (int it = 0; it < 8; ++it) {
            ushort4 u;
            u.x = f2bf(v[it].x); u.y = f2bf(v[it].y); u.z = f2bf(v[it].z); u.w = f2bf(v[it].w);
            *(ushort4*)(myC + it * 512 + ((lane << 3) ^ ((it & 7) << 4))) = u;
        }
#pragma unroll
        for (int it = 0; it < 8; ++it) v[it] = src[(8 + it) * 64 + lane];
#pragma unroll
        for (int it = 0; it < 8; ++it) {
            ushort4 u;
            u.x = f2bf(v[it].x); u.y = f2bf(v[it].y); u.z = f2bf(v[it].z); u.w = f2bf(v[it].w);
            *(ushort4*)(myC + (8 + it) * 512 + ((lane << 3) ^ ((it & 7) << 4))) = u;
        }
    }
    __asm volatile("" ::: "memory");   // order staging writes vs. fragment reads (same wave)

    // ---- GEMM1: relu(mem @ Wip + bip), 16 rows x 256 cols per wave ----
    f32x4 acc[16];
#pragma unroll
    for (int ci = 0; ci < 16; ++ci) acc[ci] = (f32x4){0.f, 0.f, 0.f, 0.f};
    __builtin_amdgcn_s_setprio(1);
#pragma unroll
    for (int t = 0; t < 8; ++t) {
        short8 af = *(const short8*)(myC + lx * 512 + ((t * 64 + quad * 16) ^ xv));
#pragma unroll
        for (int ci = 0; ci < 16; ++ci) {
            short8 bf = *(const short8*)(w1 + (((size_t)(t * 16 + ci)) * 64 + lane) * 8);
            acc[ci] = __builtin_amdgcn_mfma_f32_16x16x32_bf16(af, bf, acc[ci], 0, 0, 0);
        }
    }
    __builtin_amdgcn_s_setprio(0);

    // ---- bias + relu + per-row LN stats (rows quad*4+reg, cols all in-wave) ----
    f32x4 s2 = (f32x4){0.f, 0.f, 0.f, 0.f};
    f32x4 q2 = (f32x4){0.f, 0.f, 0.f, 0.f};
#pragma unroll
    for (int ci = 0; ci < 16; ++ci) {
        float bb = bip[ci * 16 + lx];
#pragma unroll
        for (int reg = 0; reg < 4; ++reg) {
            float v = fmaxf(acc[ci][reg] + bb, 0.f);
            acc[ci][reg] = v;
            s2[reg] += v;
            q2[reg] += v * v;
        }
    }
    float mn[4], rs[4];
#pragma unroll
    for (int reg = 0; reg < 4; ++reg) {
        float s = s2[reg], q = q2[reg];
#pragma unroll
        for (int m = 8; m >= 1; m >>= 1) { s += __shfl_xor(s, m, 64); q += __shfl_xor(q, m, 64); }
        float mean = s * (1.f / CDIM);
        float var = q * (1.f / CDIM) - mean * mean;
        mn[reg] = mean;
        rs[reg] = rsqrtf(var + EPS);
    }

    // ---- LN -> bf16 M into tile (swizzled) + packed regs for PV B-frags ----
    unsigned ypk0[16], ypk1[16];
#pragma unroll
    for (int ci = 0; ci < 16; ++ci) {
        float g = gip[ci * 16 + lx], e = beip[ci * 16 + lx];
        unsigned short u0 = f2bf((acc[ci][0] - mn[0]) * rs[0] * g + e);
        unsigned short u1 = f2bf((acc[ci][1] - mn[1]) * rs[1] * g + e);
        unsigned short u2 = f2bf((acc[ci][2] - mn[2]) * rs[2] * g + e);
        unsigned short u3 = f2bf((acc[ci][3] - mn[3]) * rs[3] * g + e);
        int cb = (ci * 16 + lx) * 2;
        int r0 = quad * 4;
        *(unsigned short*)(myC + (r0 + 0) * 512 + (cb ^ (((r0 + 0) & 7) << 4))) = u0;
        *(unsigned short*)(myC + (r0 + 1) * 512 + (cb ^ (((r0 + 1) & 7) << 4))) = u1;
        *(unsigned short*)(myC + (r0 + 2) * 512 + (cb ^ (((r0 + 2) & 7) << 4))) = u2;
        *(unsigned short*)(myC + (r0 + 3) * 512 + (cb ^ (((r0 + 3) & 7) << 4))) = u3;
        ypk0[ci] = (unsigned)u0 | ((unsigned)u1 << 16);
        ypk1[ci] = (unsigned)u2 | ((unsigned)u3 << 16);
    }
    __asm volatile("" ::: "memory");   // order M writes vs. svec fragment reads (same wave)

    // ---- scores: S(16 rows x 16 heads) = M @ w~ ----
    f32x4 accS = (f32x4){0.f, 0.f, 0.f, 0.f};
#pragma unroll
    for (int t = 0; t < 8; ++t) {
        short8 bf = *(const short8*)(wtb + ((t * 64 + lane) << 3));
        short8 af = *(const short8*)(myC + lx * 512 + ((t * 64 + quad * 16) ^ xv));
        accS = __builtin_amdgcn_mfma_f32_16x16x32_bf16(af, bf, accS, 0, 0, 0);
    }

    // lane holds head=lx, rows quad*4+reg
    float pr[4];
    float cmax = -1e30f;
#pragma unroll
    for (int reg = 0; reg < 4; ++reg) {
        float sc = (accS[reg] + qcv) * iorS[w][lx & 7][quad * 4 + reg];
        pr[reg] = sc;
        cmax = fmaxf(cmax, sc);
    }
    cmax = fmaxf(cmax, __shfl_xor(cmax, 16, 64));
    cmax = fmaxf(cmax, __shfl_xor(cmax, 32, 64));
    float csum = 0.f;
#pragma unroll
    for (int reg = 0; reg < 4; ++reg) { pr[reg] = __expf(pr[reg] - cmax); csum += pr[reg]; }
    csum += __shfl_xor(csum, 16, 64);
    csum += __shfl_xor(csum, 32, 64);

    // ---- PV: m~(16 heads x 256) = P^T(16x16) @ M(16x256), k=16 (upper half zero) ----
    // A-frag: lane(quad q<2) pa[j] = P[head=lx][row=8q+j]; quads 2,3 -> 0.
    U8 pa;
    {
        float pe[8];
#pragma unroll
        for (int j = 0; j < 8; ++j) {
            int srcl = ((((quad & 1) << 1) + (j >> 2)) << 4) | lx;
            float v = __shfl(pr[j & 3], srcl, 64);
            pe[j] = (quad < 2) ? v : 0.f;
        }
        pa.u[0] = (unsigned)f2bf(pe[0]) | ((unsigned)f2bf(pe[1]) << 16);
        pa.u[1] = (unsigned)f2bf(pe[2]) | ((unsigned)f2bf(pe[3]) << 16);
        pa.u[2] = (unsigned)f2bf(pe[4]) | ((unsigned)f2bf(pe[5]) << 16);
        pa.u[3] = (unsigned)f2bf(pe[6]) | ((unsigned)f2bf(pe[7]) << 16);
    }
    float* myF = (float*)myT;    // m~ overwrites the tile (all M reads are done)
#pragma unroll
    for (int ci = 0; ci < 16; ++ci) {
        // B-frag: ub.u[jj] = pack(M[8q+2jj][col], M[8q+2jj+1][col]), col = ci*16+lx
        U8 ub;
#pragma unroll
        for (int jj = 0; jj < 4; ++jj) {
            int srcl = ((((quad & 1) << 1) + (jj >> 1)) << 4) | lx;
            unsigned vv = (unsigned)__shfl((int)((jj & 1) ? ypk1[ci] : ypk0[ci]), srcl, 64);
            ub.u[jj] = vv;
        }
        f32x4 apv = (f32x4){0.f, 0.f, 0.f, 0.f};
        apv = __builtin_amdgcn_mfma_f32_16x16x32_bf16(pa.s8, ub.s8, apv, 0, 0, 0);
        if (quad < 2) {
#pragma unroll
            for (int reg = 0; reg < 4; ++reg) {
                int h = quad * 4 + reg;           // heads 0..7
                myF[h * 256 + ci * 16 + lx] = apv[reg];
            }
        }
    }
    if (quad == 0 && lx < 8) {
        msL[w][0][lx] = cmax;
        msL[w][1][lx] = csum;
    }
    __syncthreads();   // the ONLY barrier: all 4 waves' partials visible

    // ---- flash-merge the 4 sub-chunks -> one 64-row chunk partial ----
    {
        int h = tid >> 5, cg = tid & 31;
        float m0 = msL[0][0][h], m1 = msL[1][0][h], m2 = msL[2][0][h], m3 = msL[3][0][h];
        float mm = fmaxf(fmaxf(m0, m1), fmaxf(m2, m3));
        float e0 = __expf(m0 - mm), e1 = __expf(m1 - mm), e2 = __expf(m2 - mm), e3 = __expf(m3 - mm);
        float Sc = e0 * msL[0][1][h] + e1 * msL[1][1][h] + e2 * msL[2][1][h] + e3 * msL[3][1][h];
        const float* f0 = (const float*)&bufA[0][0];
        const float* f1 = (const float*)&bufA[1][0];
        const float* f2 = (const float*)&bufA[2][0];
        const float* f3 = (const float*)&bufA[3][0];
        size_t obase = ((((size_t)(b * NH + h)) * NCHUNK + chunk) << 8);
#pragma unroll
        for (int c = 0; c < 8; ++c) {
            int idx = h * 256 + cg * 8 + c;
            float vv = e0 * f0[idx] + e1 * f1[idx] + e2 * f2[idx] + e3 * f3[idx];
            mpart[obase + cg * 8 + c] = vv;
        }
        if (cg == 0) {
            float* d = msum + (((((size_t)(b * NH + h)) * NCHUNK + chunk)) << 1);
            d[0] = mm;
            d[1] = Sc;
        }
    }
}

// ---------------- kernel 3: flash-merge partials + V projection ----------------

__global__ __launch_bounds__(256) void combine_kernel(const float* __restrict__ mpart,
                                                      const float* __restrict__ msum,
                                                      const float* __restrict__ Wkv,
                                                      const float* __restrict__ bkv,
                                                      float* __restrict__ attnout) {
    int bh = blockIdx.x;
    int b = bh >> 3, h = bh & 7;
    int tid = threadIdx.x;
    __shared__ float ms[NCHUNK], wf[NCHUNK], mt[CDIM];
    __shared__ float sredA[4];
    __shared__ float ored[8][33];

    const float* basem = mpart + (((size_t)(b * NH + h)) * NCHUNK << 8);
    const float* bases = msum + (((size_t)(b * NH + h)) * NCHUNK << 1);
    ms[tid] = bases[tid << 1];
    __syncthreads();
    float M = -1e30f;
    for (int s = 0; s < NCHUNK; ++s) M = fmaxf(M, ms[s]);
    float e = __expf(ms[tid] - M);
    wf[tid] = e;
    float Sl = bases[(tid << 1) + 1] * e;
#pragma unroll
    for (int m = 32; m >= 1; m >>= 1) Sl += __shfl_xor(Sl, m, 64);
    if ((tid & 63) == 0) sredA[tid >> 6] = Sl;
    __syncthreads();
    float St = sredA[0] + sredA[1] + sredA[2] + sredA[3];

    float acc = 0.f;
    for (int s = 0; s < NCHUNK; ++s) acc = fmaf(wf[s], basem[((size_t)s << 8) + tid], acc);
    mt[tid] = acc / St;
    __syncthreads();

    int d = tid & 31, g = tid >> 5;
    float a2 = 0.f;
    for (int c = g * 32; c < g * 32 + 32; ++c)
        a2 = fmaf(mt[c], Wkv[(size_t)c * (2 * CDIM) + CDIM + h * 32 + d], a2);
    ored[g][d] = a2;
    __syncthreads();
    if (tid < 32) {
        float o = bkv[CDIM + h * 32 + tid];
#pragma unroll
        for (int gg2 = 0; gg2 < 8; ++gg2) o += ored[gg2][tid];
        attnout[b * CDIM + h * HD + tid] = o;
    }
}

// ---------------- kernel 4: x = attn+query; y = x + FFN(ln(x)) ----------------

__global__ __launch_bounds__(256) void epilogue_kernel(const float* __restrict__ attnout,
                                                       const float* __restrict__ query,
                                                       const float* __restrict__ gf,
                                                       const float* __restrict__ bef,
                                                       const float* __restrict__ W1,
                                                       const float* __restrict__ b1,
                                                       const float* __restrict__ W2,
                                                       const float* __restrict__ b2,
                                                       float* __restrict__ out) {
    int b = blockIdx.x;
    int tid = threadIdx.x;
    int wave = tid >> 6, lane = tid & 63;
    __shared__ float sh[FFN];
    __shared__ float red[8];

    float x = attnout[b * CDIM + tid] + query[b * CDIM + tid];
    float s = x, sq = x * x;
#pragma unroll
    for (int m = 32; m >= 1; m >>= 1) { s += __shfl_xor(s, m, 64); sq += __shfl_xor(sq, m, 64); }
    if (lane == 0) { red[wave] = s; red[4 + wave] = sq; }
    __syncthreads();
    float ts = red[0] + red[1] + red[2] + red[3];
    float tq = red[4] + red[5] + red[6] + red[7];
    float mean = ts * (1.f / CDIM);
    float var = tq * (1.f / CDIM) - mean * mean;
    float rstd = rsqrtf(var + EPS);
    sh[tid] = (x - mean) * rstd * gf[tid] + bef[tid];
    __syncthreads();

    float t[2];
#pragma unroll
    for (int i = 0; i < 2; ++i) {
        int f = tid + 256 * i;
        float a = b1[f];
        for (int k = 0; k < CDIM; ++k) a = fmaf(sh[k], W1[k * FFN + f], a);
        t[i] = 0.5f * a * (1.f + erff(a * 0.7071067811865476f));
    }
    __syncthreads();
    sh[tid] = t[0];
    sh[tid + 256] = t[1];
    __syncthreads();

    float y = b2[tid];
    for (int f = 0; f < FFN; ++f) y = fmaf(sh[f], W2[f * CDIM + tid], y);
    out[b * CDIM + tid] = x + y;
}

// ---------------- launch ----------------

extern "C" void kernel_launch(void* const* d_in, const int* in_sizes, int n_in,
                              void* d_out, int out_size, void* d_ws, size_t ws_size,
                              hipStream_t stream) {
    const float* query = (const float*)d_in[0];
    const float* mem   = (const float*)d_in[1];
    const float* ior   = (const float*)d_in[2];
    const float* Wip   = (const float*)d_in[3];
    const float* bip   = (const float*)d_in[4];
    const float* gip   = (const float*)d_in[5];
    const float* beip  = (const float*)d_in[6];
    const float* Wq    = (const float*)d_in[7];
    const float* bq    = (const float*)d_in[8];
    const float* Wkv   = (const float*)d_in[9];
    const float* bkv   = (const float*)d_in[10];
    const float* gq    = (const float*)d_in[11];
    const float* beq   = (const float*)d_in[12];
    const float* gf    = (const float*)d_in[13];
    const float* bef   = (const float*)d_in[14];
    const float* W1    = (const float*)d_in[15];
    const float* b1    = (const float*)d_in[16];
    const float* W2    = (const float*)d_in[17];
    const float* b2    = (const float*)d_in[18];
    float* out = (float*)d_out;

    char* ws = (char*)d_ws;
    float* qs             = (float*)(ws);                      // 16384 B
    float* attnout        = (float*)(ws + 16384);              // 16384 B
    float* qcb            = (float*)(ws + 32768);              // 1024 B
    unsigned short* w1sw  = (unsigned short*)(ws + 33792);     // 131072 B
    unsigned short* wtsw  = (unsigned short*)(ws + 164864);    // 131072 B
    float* mpart          = (float*)(ws + 295936);             // 16*8*256*256*4 = 33554432 B
    float* msum           = (float*)(ws + 295936 + 33554432);  // 16*8*256*2*4 = 131072 B
    // total: 33981440 B

    const int B = 16;

    convert_weights<<<256, 256, 0, stream>>>(Wip, w1sw);
    qprep_kernel<<<B, 256, 0, stream>>>(query, Wq, bq, gq, beq, Wkv, bkv, qs, wtsw, qcb);
    main_kernel<<<B * NCHUNK, 256, 0, stream>>>(mem, w1sw, wtsw, bip, gip, beip, qcb, ior, mpart, msum);
    combine_kernel<<<B * NH, 256, 0, stream>>>(mpart, msum, Wkv, bkv, attnout);
    epilogue_kernel<<<B, 256, 0, stream>>>(attnout, query, gf, bef, W1, b1, W2, b2, out);
}